// Round 10
// baseline (142.777 us; speedup 1.0000x reference)
//
#include <hip/hip_runtime.h>
#include <stdint.h>

#define N 8192
#define D 256          // elements per row == bytes per fp8 row
#define INV_T 20.0f
#define LOG2E 1.44269504088896340736f
#define BM 128
#define BN 128
#define NXB 64         // col-blocks (N/BN)

typedef __attribute__((ext_vector_type(16))) float f32x16;
typedef __attribute__((ext_vector_type(4))) int i32x4;
typedef __attribute__((ext_vector_type(8))) int i32x8;

typedef __attribute__((address_space(3))) uint32_t lds_u32;
typedef __attribute__((address_space(1))) const uint32_t gbl_u32;

// Raw v_exp_f32 (2^x). Library exp2f carries a multi-instruction guard for
// |x|>~126; our args are bounded, so the raw trans op is safe (verified r5).
static __device__ __forceinline__ float fast_exp2(float x) {
  float r;
  asm("v_exp_f32 %0, %1" : "=v"(r) : "v"(x));
  return r;
}

// DPP-fused butterfly add levels (bit-identical to __shfl_xor tree, r4/r5).
#define DPP_ADD(v, ctrl)                                                      \
  ((v) + __builtin_bit_cast(float, __builtin_amdgcn_update_dpp(               \
             0, __builtin_bit_cast(int, (v)), (ctrl), 0xf, 0xf, true)))

// Kernel 1: per-row fp32 normalize -> fp8 e4m3 copies (HW cvt, OCP on gfx950);
// c[i] = (e_i . p_i)/T exact fp32. Zeroes out (stream-ordered; replay-safe).
__global__ __launch_bounds__(256) void normalize_kernel(
    const float* __restrict__ e, const float* __restrict__ p, const float* __restrict__ n,
    uint32_t* __restrict__ eb, uint32_t* __restrict__ pb, uint32_t* __restrict__ nb,
    float* __restrict__ cbuf, float* __restrict__ out) {
  const int tid = threadIdx.x;
  const int wave = tid >> 6, lane = tid & 63;
  const int row = blockIdx.x * 4 + wave;          // one wave per row

  if (blockIdx.x == 0 && tid == 0) out[0] = 0.0f;

  const float4 ev = ((const float4*)(e + (size_t)row * D))[lane];
  const float4 pv = ((const float4*)(p + (size_t)row * D))[lane];
  const float4 nv = ((const float4*)(n + (size_t)row * D))[lane];

  float sse = ev.x*ev.x + ev.y*ev.y + ev.z*ev.z + ev.w*ev.w;
  float ssp = pv.x*pv.x + pv.y*pv.y + pv.z*pv.z + pv.w*pv.w;
  float ssn = nv.x*nv.x + nv.y*nv.y + nv.z*nv.z + nv.w*nv.w;
  float dep = ev.x*pv.x + ev.y*pv.y + ev.z*pv.z + ev.w*pv.w;
#pragma unroll
  for (int m = 1; m < 64; m <<= 1) {
    sse += __shfl_xor(sse, m);
    ssp += __shfl_xor(ssp, m);
    ssn += __shfl_xor(ssn, m);
    dep += __shfl_xor(dep, m);
  }
  const float se = 1.0f / fmaxf(sqrtf(sse), 1e-8f);
  const float sp = 1.0f / fmaxf(sqrtf(ssp), 1e-8f);
  const float sn = 1.0f / fmaxf(sqrtf(ssn), 1e-8f);

  int ue = __builtin_amdgcn_cvt_pk_fp8_f32(ev.x*se, ev.y*se, 0, false);
  ue     = __builtin_amdgcn_cvt_pk_fp8_f32(ev.z*se, ev.w*se, ue, true);
  int up = __builtin_amdgcn_cvt_pk_fp8_f32(pv.x*sp, pv.y*sp, 0, false);
  up     = __builtin_amdgcn_cvt_pk_fp8_f32(pv.z*sp, pv.w*sp, up, true);
  int un = __builtin_amdgcn_cvt_pk_fp8_f32(nv.x*sn, nv.y*sn, 0, false);
  un     = __builtin_amdgcn_cvt_pk_fp8_f32(nv.z*sn, nv.w*sn, un, true);
  eb[row * 64 + lane] = (uint32_t)ue;             // 64 uints = 256 fp8 bytes per row
  pb[row * 64 + lane] = (uint32_t)up;
  nb[row * 64 + lane] = (uint32_t)un;

  if (lane == 0) cbuf[row] = dep * se * sp * INV_T;
}

// Kernel 2: 128x128-tile fp8 GEMM (X @ Y^T) with fused exp row-sums.
// EXACT round-5 core (measured 58.4 us, VGPR 52, 0 bank conflicts, no spill):
//  - B staged full-K (32 KB, single buffer, ONE barrier) via global_load_lds,
//    16-slot XOR layout: group gg of row r at slot gg^(r&15) (read XORs again
//    -> canonical K-order; involution). Measured conflict-free.
//  - A direct to registers (8 x dwordx4 per lane; block footprint 32 KB, L1/L2).
//  - MX-scaled MFMA 32x32x64_f8f6f4 (fmt 0 = e4m3, unit scales): bit-exact vs
//    non-scaled fp8 at 2x rate. Raw v_exp_f32 + XOR-folded B addresses.
//  - S-MAJOR K loop (4 independent acc chains = in-wave MFMA ILP; r9's
//    ni-major serialization regressed 58.4->61.6 and is reverted).
//  - 3 blocks/CU, free-drifting (no inter-tile barriers) -> pipes stay mixed.
__global__ __launch_bounds__(256, 3) void simexp_kernel(
    const uint8_t* __restrict__ eb, const uint8_t* __restrict__ pb,
    const uint8_t* __restrict__ nb, const float* __restrict__ cbuf,
    float* __restrict__ part) {
  __shared__ uint8_t Bs[BN * D];    // 32 KB, full-K B tile (swizzled)
  __shared__ float cs[BM];          // 512 B

  const int z = blockIdx.z;
  const uint8_t* __restrict__ A = z ? pb : eb;
  const uint8_t* __restrict__ B = z ? eb : nb;

  const int tid = threadIdx.x;
  const int wave = tid >> 6, lane = tid & 63;
  const int lane31 = lane & 31, half = lane >> 5;
  const int rowTile = blockIdx.x * BM, colblk = blockIdx.y;
  const int colTile = colblk * BN;

  // ---- stage B (full K): 2048 16B chunks, 8 per thread, coalesced ----
#pragma unroll
  for (int i = 0; i < 8; ++i) {
    const int c = i * 256 + tid, r = c >> 4, sl = c & 15;
    const int gg = sl ^ (r & 15);               // swizzled SOURCE group
    __builtin_amdgcn_global_load_lds(
        (gbl_u32*)(B + (size_t)(colTile + r) * D + gg * 16),
        (lds_u32*)&Bs[c * 16], 16, 0, 0);
  }

  // ---- A direct to registers: this lane's row, its K-half, all 4 K-steps ----
  const int arow = rowTile + wave * 32 + lane31;
  const uint8_t* __restrict__ Arow = A + (size_t)arow * D + half * 32;
  i32x8 afr[4];
#pragma unroll
  for (int s = 0; s < 4; ++s) {
    const i32x4 lo = *(const i32x4*)(Arow + s * 64);
    const i32x4 hi = *(const i32x4*)(Arow + s * 64 + 16);
    afr[s] = (i32x8){lo[0], lo[1], lo[2], lo[3], hi[0], hi[1], hi[2], hi[3]};
  }

  if (tid < BM) cs[tid] = cbuf[rowTile + tid] * LOG2E;

  // per-ni XOR-folded B fragment base addresses (byte offsets into Bs)
  int bbase[4];
#pragma unroll
  for (int ni = 0; ni < 4; ++ni) {
    const int cl = ni * 32 + lane31;
    bbase[ni] = (cl << 8) ^ ((cl & 15) << 4) ^ (half << 5);
  }

  f32x16 acc[4];
#pragma unroll
  for (int ni = 0; ni < 4; ++ni)
#pragma unroll
    for (int r = 0; r < 16; ++r) acc[ni][r] = 0.0f;

  __syncthreads();   // the ONLY barrier: B tile + cs visible

  // ---- K loop: 4 steps of K=64, zero barriers, compiler free to pipeline ----
#pragma unroll
  for (int s = 0; s < 4; ++s) {
#pragma unroll
    for (int ni = 0; ni < 4; ++ni) {
      const int alo = bbase[ni] ^ (s << 6);     // 1 v_xor (s<<6 is inline const)
      const i32x4 blo = *(const i32x4*)&Bs[alo];
      const i32x4 bhi = *(const i32x4*)&Bs[alo ^ 16];
      const i32x8 b = (i32x8){blo[0], blo[1], blo[2], blo[3],
                              bhi[0], bhi[1], bhi[2], bhi[3]};
      acc[ni] = __builtin_amdgcn_mfma_scale_f32_32x32x64_f8f6f4(
          afr[s], b, acc[ni],
          0 /*A fmt fp8*/, 0 /*B fmt fp8*/,
          0, 0x7F7F7F7F /*scaleA=1*/, 0, 0x7F7F7F7F /*scaleB=1*/);
    }
  }

  // ---- epilogue: exp2 + row-sum over this wave's 128 cols ----
  // 32x32 C/D: col=lane&31, row=(reg&3)+8*(reg>>2)+4*(lane>>5) (m74/m101).
  const float K2 = INV_T * LOG2E;
#pragma unroll
  for (int reg = 0; reg < 16; ++reg) {
    const int rlocal = (reg & 3) + 8 * (reg >> 2) + 4 * half;
    const int rowl = wave * 32 + rlocal;
    const float cv = cs[rowl];
    float v = fast_exp2(acc[0][reg] * K2 - cv) + fast_exp2(acc[1][reg] * K2 - cv) +
              fast_exp2(acc[2][reg] * K2 - cv) + fast_exp2(acc[3][reg] * K2 - cv);
    v = DPP_ADD(v, 0xB1);    // xor1: quad_perm [1,0,3,2]
    v = DPP_ADD(v, 0x4E);    // xor2: quad_perm [2,3,0,1]
    v = DPP_ADD(v, 0x141);   // xor4: row_half_mirror
    v = DPP_ADD(v, 0x140);   // xor8: row_mirror
    v += __builtin_bit_cast(float, __builtin_amdgcn_ds_swizzle(
             __builtin_bit_cast(int, v), 0x401F));  // xor16
    if (lane31 == 0) {
      part[((size_t)(z * NXB + colblk)) * N + rowTile + rowl] = v;
    }
  }
}

// Kernel 3 (finalize): per-row sum of 64 partials -> log/log1p -> wave reduce
// -> one atomicAdd per 64-thread block (256 atomics to out). No fences needed:
// part is written with plain stores; the launch boundary orders visibility.
// r10: FULL unroll (all 64 loads in flight at 1 wave/CU, latency-bound) and
// 4-way split add chains (reorder tolerated: r8's atomics passed absmax 0).
__global__ __launch_bounds__(64) void finalize_kernel(const float* __restrict__ part,
                                                      float* __restrict__ out) {
  const int r = blockIdx.x * 64 + threadIdx.x;    // 256 x 64 = 16384 (z,row) pairs
  const int z = r >> 13, row = r & (N - 1);
  const float* __restrict__ base = part + (size_t)(z * NXB) * N + row;
  float s0 = 0.0f, s1 = 0.0f, s2 = 0.0f, s3 = 0.0f;
#pragma unroll
  for (int x = 0; x < NXB; x += 4) {
    s0 += base[(size_t)(x + 0) * N];
    s1 += base[(size_t)(x + 1) * N];
    s2 += base[(size_t)(x + 2) * N];
    s3 += base[(size_t)(x + 3) * N];
  }
  const float s = (s0 + s1) + (s2 + s3);
  float val = z ? logf(s) : log1pf(s);
#pragma unroll
  for (int m = 1; m < 64; m <<= 1) val += __shfl_xor(val, m);
  if (threadIdx.x == 0) atomicAdd(out, val * (1.0f / (float)N));
}

extern "C" void kernel_launch(void* const* d_in, const int* in_sizes, int n_in,
                              void* d_out, int out_size, void* d_ws, size_t ws_size,
                              hipStream_t stream) {
  const float* e = (const float*)d_in[0];
  const float* p = (const float*)d_in[1];
  const float* n = (const float*)d_in[2];

  char* w = (char*)d_ws;
  uint8_t* eb = (uint8_t*)w;                                     // 2 MB
  uint8_t* pb = eb + (size_t)N * D;                              // 2 MB
  uint8_t* nb = pb + (size_t)N * D;                              // 2 MB
  float* cbuf = (float*)(nb + (size_t)N * D);                    // 32 KB
  float* part = cbuf + N;                                        // 4 MB

  normalize_kernel<<<N / 4, 256, 0, stream>>>(e, p, n, (uint32_t*)eb, (uint32_t*)pb,
                                              (uint32_t*)nb, cbuf, (float*)d_out);
  simexp_kernel<<<dim3(N / BM, N / BN, 2), 256, 0, stream>>>(eb, pb, nb, cbuf, part);
  finalize_kernel<<<256, 64, 0, stream>>>(part, (float*)d_out);
}

// Round 11
// 134.084 us; speedup vs baseline: 1.0648x; 1.0648x over previous
//
#include <hip/hip_runtime.h>
#include <stdint.h>

#define N 8192
#define D 256          // elements per row == bytes per fp8 row
#define INV_T 20.0f
#define LOG2E 1.44269504088896340736f
#define BM 128
#define BN 128
#define NXB 64         // col-blocks (N/BN)

typedef __attribute__((ext_vector_type(16))) float f32x16;
typedef __attribute__((ext_vector_type(4))) int i32x4;
typedef __attribute__((ext_vector_type(8))) int i32x8;

typedef __attribute__((address_space(3))) uint32_t lds_u32;
typedef __attribute__((address_space(1))) const uint32_t gbl_u32;

// Raw v_exp_f32 (2^x). Library exp2f carries a multi-instruction guard for
// |x|>~126; our args are bounded, so the raw trans op is safe (verified r5).
static __device__ __forceinline__ float fast_exp2(float x) {
  float r;
  asm("v_exp_f32 %0, %1" : "=v"(r) : "v"(x));
  return r;
}

// Kernel 1: per-row fp32 normalize -> fp8 e4m3 copies (HW cvt, OCP on gfx950);
// c[i] = (e_i . p_i)/T exact fp32. Zeroes out (stream-ordered; replay-safe).
__global__ __launch_bounds__(256) void normalize_kernel(
    const float* __restrict__ e, const float* __restrict__ p, const float* __restrict__ n,
    uint32_t* __restrict__ eb, uint32_t* __restrict__ pb, uint32_t* __restrict__ nb,
    float* __restrict__ cbuf, float* __restrict__ out) {
  const int tid = threadIdx.x;
  const int wave = tid >> 6, lane = tid & 63;
  const int row = blockIdx.x * 4 + wave;          // one wave per row

  if (blockIdx.x == 0 && tid == 0) out[0] = 0.0f;

  const float4 ev = ((const float4*)(e + (size_t)row * D))[lane];
  const float4 pv = ((const float4*)(p + (size_t)row * D))[lane];
  const float4 nv = ((const float4*)(n + (size_t)row * D))[lane];

  float sse = ev.x*ev.x + ev.y*ev.y + ev.z*ev.z + ev.w*ev.w;
  float ssp = pv.x*pv.x + pv.y*pv.y + pv.z*pv.z + pv.w*pv.w;
  float ssn = nv.x*nv.x + nv.y*nv.y + nv.z*nv.z + nv.w*nv.w;
  float dep = ev.x*pv.x + ev.y*pv.y + ev.z*pv.z + ev.w*pv.w;
#pragma unroll
  for (int m = 1; m < 64; m <<= 1) {
    sse += __shfl_xor(sse, m);
    ssp += __shfl_xor(ssp, m);
    ssn += __shfl_xor(ssn, m);
    dep += __shfl_xor(dep, m);
  }
  const float se = 1.0f / fmaxf(sqrtf(sse), 1e-8f);
  const float sp = 1.0f / fmaxf(sqrtf(ssp), 1e-8f);
  const float sn = 1.0f / fmaxf(sqrtf(ssn), 1e-8f);

  int ue = __builtin_amdgcn_cvt_pk_fp8_f32(ev.x*se, ev.y*se, 0, false);
  ue     = __builtin_amdgcn_cvt_pk_fp8_f32(ev.z*se, ev.w*se, ue, true);
  int up = __builtin_amdgcn_cvt_pk_fp8_f32(pv.x*sp, pv.y*sp, 0, false);
  up     = __builtin_amdgcn_cvt_pk_fp8_f32(pv.z*sp, pv.w*sp, up, true);
  int un = __builtin_amdgcn_cvt_pk_fp8_f32(nv.x*sn, nv.y*sn, 0, false);
  un     = __builtin_amdgcn_cvt_pk_fp8_f32(nv.z*sn, nv.w*sn, un, true);
  eb[row * 64 + lane] = (uint32_t)ue;             // 64 uints = 256 fp8 bytes per row
  pb[row * 64 + lane] = (uint32_t)up;
  nb[row * 64 + lane] = (uint32_t)un;

  if (lane == 0) cbuf[row] = dep * se * sp * INV_T;
}

// Kernel 2: 128x128-tile fp8 GEMM (X @ Y^T) with fused exp row-sums.
// r5 core (full-K single-buffer B via global_load_lds with the 16-slot XOR
// layout = 0 bank conflicts; A direct-to-registers; MX-scaled MFMA
// 32x32x64_f8f6f4 = bit-exact 2x fp8 rate; s-major K loop for 4-chain MFMA
// ILP; raw v_exp_f32; XOR-folded B addresses; ONE barrier) with the MFMA
// OPERANDS SWAPPED (r11): acc = mfma(b_frag, a_frag) computes the transposed
// tile, so reg -> B-col and LANE -> A-ROW. Each lane then owns one output
// row: the row-sum is 63 in-lane adds (4 ILP chains) + ONE __shfl_xor(v,32)
// -- the entire 5-level DPP/ds_swizzle butterfly (144 VALU instrs/wave) is
// deleted, cv becomes a per-lane scalar straight from cbuf (cs LDS gone),
// and the part store is one coalesced 128B store per wave. Operand register
// layouts for the MFMA A/B slots are symmetric (lane->row / lane->col with
// identical K-grouping), so fragment construction is unchanged.
__global__ __launch_bounds__(256, 3) void simexp_kernel(
    const uint8_t* __restrict__ eb, const uint8_t* __restrict__ pb,
    const uint8_t* __restrict__ nb, const float* __restrict__ cbuf,
    float* __restrict__ part) {
  __shared__ uint8_t Bs[BN * D];    // 32 KB, full-K B tile (swizzled)

  const int z = blockIdx.z;
  const uint8_t* __restrict__ A = z ? pb : eb;
  const uint8_t* __restrict__ B = z ? eb : nb;

  const int tid = threadIdx.x;
  const int wave = tid >> 6, lane = tid & 63;
  const int lane31 = lane & 31, half = lane >> 5;
  const int rowTile = blockIdx.x * BM, colblk = blockIdx.y;
  const int colTile = colblk * BN;

  // ---- stage B (full K): 2048 16B chunks, 8 per thread, coalesced ----
#pragma unroll
  for (int i = 0; i < 8; ++i) {
    const int c = i * 256 + tid, r = c >> 4, sl = c & 15;
    const int gg = sl ^ (r & 15);               // swizzled SOURCE group
    __builtin_amdgcn_global_load_lds(
        (gbl_u32*)(B + (size_t)(colTile + r) * D + gg * 16),
        (lds_u32*)&Bs[c * 16], 16, 0, 0);
  }

  // ---- A direct to registers: this lane's row, its K-half, all 4 K-steps ----
  const int arow = rowTile + wave * 32 + lane31;
  const uint8_t* __restrict__ Arow = A + (size_t)arow * D + half * 32;
  i32x8 afr[4];
#pragma unroll
  for (int s = 0; s < 4; ++s) {
    const i32x4 lo = *(const i32x4*)(Arow + s * 64);
    const i32x4 hi = *(const i32x4*)(Arow + s * 64 + 16);
    afr[s] = (i32x8){lo[0], lo[1], lo[2], lo[3], hi[0], hi[1], hi[2], hi[3]};
  }

  // per-lane diag term (this lane's output row after the operand swap)
  const float cv = cbuf[arow] * LOG2E;

  // per-ni XOR-folded B fragment base addresses (byte offsets into Bs)
  int bbase[4];
#pragma unroll
  for (int ni = 0; ni < 4; ++ni) {
    const int cl = ni * 32 + lane31;
    bbase[ni] = (cl << 8) ^ ((cl & 15) << 4) ^ (half << 5);
  }

  f32x16 acc[4];
#pragma unroll
  for (int ni = 0; ni < 4; ++ni)
#pragma unroll
    for (int r = 0; r < 16; ++r) acc[ni][r] = 0.0f;

  __syncthreads();   // the ONLY barrier: B tile visible

  // ---- K loop: 4 steps of K=64, zero barriers; SWAPPED operand order ----
#pragma unroll
  for (int s = 0; s < 4; ++s) {
#pragma unroll
    for (int ni = 0; ni < 4; ++ni) {
      const int alo = bbase[ni] ^ (s << 6);     // 1 v_xor (s<<6 is inline const)
      const i32x4 blo = *(const i32x4*)&Bs[alo];
      const i32x4 bhi = *(const i32x4*)&Bs[alo ^ 16];
      const i32x8 b = (i32x8){blo[0], blo[1], blo[2], blo[3],
                              bhi[0], bhi[1], bhi[2], bhi[3]};
      acc[ni] = __builtin_amdgcn_mfma_scale_f32_32x32x64_f8f6f4(
          b, afr[s], acc[ni],                   // SWAPPED: out = (B A^T) = S^T
          0 /*fmt fp8*/, 0 /*fmt fp8*/,
          0, 0x7F7F7F7F /*scale=1*/, 0, 0x7F7F7F7F /*scale=1*/);
    }
  }

  // ---- epilogue: exp2 + IN-LANE row-sum (lane owns row arow) ----
  const float K2 = INV_T * LOG2E;
  float sacc0 = 0.0f, sacc1 = 0.0f, sacc2 = 0.0f, sacc3 = 0.0f;
#pragma unroll
  for (int reg = 0; reg < 16; ++reg) {
    sacc0 += fast_exp2(acc[0][reg] * K2 - cv);
    sacc1 += fast_exp2(acc[1][reg] * K2 - cv);
    sacc2 += fast_exp2(acc[2][reg] * K2 - cv);
    sacc3 += fast_exp2(acc[3][reg] * K2 - cv);
  }
  float v = (sacc0 + sacc1) + (sacc2 + sacc3);   // this lane's 64 cols
  v += __shfl_xor(v, 32);                        // + other K-half's 64 cols
  if (lane < 32)                                 // coalesced 128B store per wave
    part[((size_t)(z * NXB + colblk)) * N + rowTile + wave * 32 + lane] = v;
}

// Kernel 3 (finalize): per-row sum of 64 partials -> log/log1p -> wave reduce
// -> one atomicAdd per 64-thread block (256 atomics to out). No fences needed:
// part is written with plain stores; the launch boundary orders visibility.
__global__ __launch_bounds__(64) void finalize_kernel(const float* __restrict__ part,
                                                      float* __restrict__ out) {
  const int r = blockIdx.x * 64 + threadIdx.x;    // 256 x 64 = 16384 (z,row) pairs
  const int z = r >> 13, row = r & (N - 1);
  const float* __restrict__ base = part + (size_t)(z * NXB) * N + row;
  float s0 = 0.0f, s1 = 0.0f, s2 = 0.0f, s3 = 0.0f;
#pragma unroll
  for (int x = 0; x < NXB; x += 4) {
    s0 += base[(size_t)(x + 0) * N];
    s1 += base[(size_t)(x + 1) * N];
    s2 += base[(size_t)(x + 2) * N];
    s3 += base[(size_t)(x + 3) * N];
  }
  const float s = (s0 + s1) + (s2 + s3);
  float val = z ? logf(s) : log1pf(s);
#pragma unroll
  for (int m = 1; m < 64; m <<= 1) val += __shfl_xor(val, m);
  if (threadIdx.x == 0) atomicAdd(out, val * (1.0f / (float)N));
}

extern "C" void kernel_launch(void* const* d_in, const int* in_sizes, int n_in,
                              void* d_out, int out_size, void* d_ws, size_t ws_size,
                              hipStream_t stream) {
  const float* e = (const float*)d_in[0];
  const float* p = (const float*)d_in[1];
  const float* n = (const float*)d_in[2];

  char* w = (char*)d_ws;
  uint8_t* eb = (uint8_t*)w;                                     // 2 MB
  uint8_t* pb = eb + (size_t)N * D;                              // 2 MB
  uint8_t* nb = pb + (size_t)N * D;                              // 2 MB
  float* cbuf = (float*)(nb + (size_t)N * D);                    // 32 KB
  float* part = cbuf + N;                                        // 4 MB

  normalize_kernel<<<N / 4, 256, 0, stream>>>(e, p, n, (uint32_t*)eb, (uint32_t*)pb,
                                              (uint32_t*)nb, cbuf, (float*)d_out);
  simexp_kernel<<<dim3(N / BM, N / BN, 2), 256, 0, stream>>>(eb, pb, nb, cbuf, part);
  finalize_kernel<<<256, 64, 0, stream>>>(part, (float*)d_out);
}

// Round 12
// 117.506 us; speedup vs baseline: 1.2151x; 1.1411x over previous
//
#include <hip/hip_runtime.h>
#include <stdint.h>

#define N 8192
#define D 256          // elements per row == bytes per fp8 row
#define INV_T 20.0f
#define LOG2E 1.44269504088896340736f
#define BM 128
#define BN 128
#define NCHUNK 4       // col-chunks (grid.x)
#define NT 16          // col-tiles per chunk; NCHUNK*NT*BN == N

typedef __attribute__((ext_vector_type(16))) float f32x16;
typedef __attribute__((ext_vector_type(4))) int i32x4;
typedef __attribute__((ext_vector_type(8))) int i32x8;

typedef __attribute__((address_space(3))) uint32_t lds_u32;
typedef __attribute__((address_space(1))) const uint32_t gbl_u32;

// Raw v_exp_f32 (2^x). Args bounded -> no OCML guard needed (verified r5).
static __device__ __forceinline__ float fast_exp2(float x) {
  float r;
  asm("v_exp_f32 %0, %1" : "=v"(r) : "v"(x));
  return r;
}

// Kernel 1: per-row fp32 normalize -> fp8 e4m3 copies (HW cvt, OCP on gfx950);
// c[i] = (e_i . p_i)/T exact fp32. Zeroes out (stream-ordered; replay-safe).
__global__ __launch_bounds__(256) void normalize_kernel(
    const float* __restrict__ e, const float* __restrict__ p, const float* __restrict__ n,
    uint32_t* __restrict__ eb, uint32_t* __restrict__ pb, uint32_t* __restrict__ nb,
    float* __restrict__ cbuf, float* __restrict__ out) {
  const int tid = threadIdx.x;
  const int wave = tid >> 6, lane = tid & 63;
  const int row = blockIdx.x * 4 + wave;          // one wave per row

  if (blockIdx.x == 0 && tid == 0) out[0] = 0.0f;

  const float4 ev = ((const float4*)(e + (size_t)row * D))[lane];
  const float4 pv = ((const float4*)(p + (size_t)row * D))[lane];
  const float4 nv = ((const float4*)(n + (size_t)row * D))[lane];

  float sse = ev.x*ev.x + ev.y*ev.y + ev.z*ev.z + ev.w*ev.w;
  float ssp = pv.x*pv.x + pv.y*pv.y + pv.z*pv.z + pv.w*pv.w;
  float ssn = nv.x*nv.x + nv.y*nv.y + nv.z*nv.z + nv.w*nv.w;
  float dep = ev.x*pv.x + ev.y*pv.y + ev.z*pv.z + ev.w*pv.w;
#pragma unroll
  for (int m = 1; m < 64; m <<= 1) {
    sse += __shfl_xor(sse, m);
    ssp += __shfl_xor(ssp, m);
    ssn += __shfl_xor(ssn, m);
    dep += __shfl_xor(dep, m);
  }
  const float se = 1.0f / fmaxf(sqrtf(sse), 1e-8f);
  const float sp = 1.0f / fmaxf(sqrtf(ssp), 1e-8f);
  const float sn = 1.0f / fmaxf(sqrtf(ssn), 1e-8f);

  int ue = __builtin_amdgcn_cvt_pk_fp8_f32(ev.x*se, ev.y*se, 0, false);
  ue     = __builtin_amdgcn_cvt_pk_fp8_f32(ev.z*se, ev.w*se, ue, true);
  int up = __builtin_amdgcn_cvt_pk_fp8_f32(pv.x*sp, pv.y*sp, 0, false);
  up     = __builtin_amdgcn_cvt_pk_fp8_f32(pv.z*sp, pv.w*sp, up, true);
  int un = __builtin_amdgcn_cvt_pk_fp8_f32(nv.x*sn, nv.y*sn, 0, false);
  un     = __builtin_amdgcn_cvt_pk_fp8_f32(nv.z*sn, nv.w*sn, un, true);
  eb[row * 64 + lane] = (uint32_t)ue;             // 64 uints = 256 fp8 bytes per row
  pb[row * 64 + lane] = (uint32_t)up;
  nb[row * 64 + lane] = (uint32_t)un;

  if (lane == 0) cbuf[row] = dep * se * sp * INV_T;
}

// Kernel 2: PERSISTENT col-walk fp8 GEMM (X @ Y^T) with fused exp row-sums.
// = r7's counted-vmcnt pipeline rebuilt on the r11 swapped core, which shrinks
// the cross-tile live state that made r7 spill (sums 16->4, cv 16->1, stores
// 16 scattered -> 1 coalesced). 512 blocks (2/CU, ONE dispatch batch): fixed
// rowTile, walk 16 col-tiles:
//  - B double-buffered (2 x 32 KB full-K tiles, 16-slot XOR layout = 0 bank
//    conflicts, r1-r11). Counted "s_waitcnt vmcnt(8)": exactly one B-tile in
//    flight; never drained mid-loop; stage of B(t+2) issued before the
//    epilogue exp so HBM/L2 latency hides under VALU (T3/T4/T14).
//  - A-frags (32 VGPR) + per-lane cv (1 VGPR) loaded ONCE; issue-order pinned
//    (sched_barrier) so the vmcnt retire arithmetic is exact (FIFO retire).
//  - SWAPPED MFMA (r11): acc = mfma(b, afr) -> lane owns A-row; row-sum is
//    in-lane adds + one shfl_xor(32) + one coalesced store per block.
//  - MX-scaled MFMA 32x32x64_f8f6f4 (e4m3, unit scales): bit-exact, 2x rate.
// Spill sentinels: VGPR ~130-150, WRITE_SIZE ~4 MB (r7 failed at 128/9.5MB).
__global__ __launch_bounds__(256, 2) void simexp_kernel(
    const uint8_t* __restrict__ eb, const uint8_t* __restrict__ pb,
    const uint8_t* __restrict__ nb, const float* __restrict__ cbuf,
    float* __restrict__ part) {
  __shared__ uint8_t Bs[2][BN * D];   // 64 KB

  const int z = blockIdx.z;
  const uint8_t* __restrict__ A = z ? pb : eb;
  const uint8_t* __restrict__ B = z ? eb : nb;

  const int tid = threadIdx.x;
  const int wave = tid >> 6, lane = tid & 63;
  const int lane31 = lane & 31, half = lane >> 5;
  const int chunk = blockIdx.x;
  const int rowTile = blockIdx.y * BM;
  const int colblk0 = chunk * NT;

#define STAGEB(buf, cblk)                                                     \
  do {                                                                        \
    const uint8_t* __restrict__ Bsrc = B + (size_t)(cblk) * (BN * D);         \
    _Pragma("unroll") for (int i = 0; i < 8; ++i) {                           \
      const int c = i * 256 + tid, r = c >> 4, sl = c & 15;                   \
      const int gg = sl ^ (r & 15);                                           \
      __builtin_amdgcn_global_load_lds(                                       \
          (gbl_u32*)(Bsrc + (size_t)r * D + gg * 16),                         \
          (lds_u32*)&Bs[buf][c * 16], 16, 0, 0);                              \
    }                                                                         \
  } while (0)

  // ---- prologue: A-frags + cv FIRST (oldest in the vmem FIFO), then B0, B1 ----
  const int arow = rowTile + wave * 32 + lane31;
  const uint8_t* __restrict__ Arow = A + (size_t)arow * D + half * 32;
  i32x8 afr[4];
#pragma unroll
  for (int s = 0; s < 4; ++s) {
    const i32x4 lo = *(const i32x4*)(Arow + s * 64);
    const i32x4 hi = *(const i32x4*)(Arow + s * 64 + 16);
    afr[s] = (i32x8){lo[0], lo[1], lo[2], lo[3], hi[0], hi[1], hi[2], hi[3]};
  }
  const float cv = cbuf[arow] * LOG2E;
  __builtin_amdgcn_sched_barrier(0);   // pin A/cv issue BEFORE the stages
  STAGEB(0, colblk0 + 0);
  STAGEB(1, colblk0 + 1);
  __builtin_amdgcn_sched_barrier(0);   // pin stages above the loop

  // per-ni XOR-folded B fragment base addresses (bit 15 = buffer parity, clear)
  int bbase[4];
#pragma unroll
  for (int ni = 0; ni < 4; ++ni) {
    const int cl = ni * 32 + lane31;
    bbase[ni] = (cl << 8) ^ ((cl & 15) << 4) ^ (half << 5);
  }

  const float K2 = INV_T * LOG2E;
  float sacc0 = 0.0f, sacc1 = 0.0f, sacc2 = 0.0f, sacc3 = 0.0f;

#pragma unroll 1
  for (int t = 0; t < NT; ++t) {
    // B_t landed when <=8 vmem outstanding (FIFO retire: A+cv+B..t all in).
    if (t < NT - 1) asm volatile("s_waitcnt vmcnt(8)" ::: "memory");
    else            asm volatile("s_waitcnt vmcnt(0)" ::: "memory");
    __builtin_amdgcn_s_barrier();
    __builtin_amdgcn_sched_barrier(0);

    const int bpar = (t & 1) << 15;
    f32x16 acc[4];
#pragma unroll
    for (int ni = 0; ni < 4; ++ni)
#pragma unroll
      for (int r = 0; r < 16; ++r) acc[ni][r] = 0.0f;

#pragma unroll
    for (int s = 0; s < 4; ++s) {
#pragma unroll
      for (int ni = 0; ni < 4; ++ni) {
        const int alo = (bbase[ni] ^ bpar) ^ (s << 6);
        const i32x4 blo = *(const i32x4*)&Bs[0][alo];
        const i32x4 bhi = *(const i32x4*)&Bs[0][alo ^ 16];
        const i32x8 b = (i32x8){blo[0], blo[1], blo[2], blo[3],
                                bhi[0], bhi[1], bhi[2], bhi[3]};
        acc[ni] = __builtin_amdgcn_mfma_scale_f32_32x32x64_f8f6f4(
            b, afr[s], acc[ni],                 // SWAPPED: lane -> A-row
            0 /*fmt fp8*/, 0 /*fmt fp8*/,
            0, 0x7F7F7F7F /*scale=1*/, 0, 0x7F7F7F7F /*scale=1*/);
      }
    }

    __builtin_amdgcn_sched_barrier(0);
    __builtin_amdgcn_s_barrier();   // all waves done reading buf (t&1)
    __builtin_amdgcn_sched_barrier(0);

    if (t + 2 < NT) STAGEB(t & 1, colblk0 + t + 2);  // refill vacated buffer

    // exp-accumulate (VALU) overlaps the staging just issued.
#pragma unroll
    for (int reg = 0; reg < 16; ++reg) {
      sacc0 += fast_exp2(acc[0][reg] * K2 - cv);
      sacc1 += fast_exp2(acc[1][reg] * K2 - cv);
      sacc2 += fast_exp2(acc[2][reg] * K2 - cv);
      sacc3 += fast_exp2(acc[3][reg] * K2 - cv);
    }
  }
#undef STAGEB

  // ---- once per block: combine halves + ONE coalesced 128B store/wave ----
  float v = (sacc0 + sacc1) + (sacc2 + sacc3);   // this lane's 64*NT cols
  v += __shfl_xor(v, 32);                        // + the other col-half set
  if (lane < 32)
    part[((size_t)(z * NCHUNK + chunk)) * N + rowTile + wave * 32 + lane] = v;
}

// Kernel 3 (finalize): per-row sum of 4 partials -> log/log1p -> wave reduce
// -> one atomicAdd per 64-thread block (256 atomics to out). No fences needed:
// part is written with plain stores; the launch boundary orders visibility.
__global__ __launch_bounds__(64) void finalize_kernel(const float* __restrict__ part,
                                                      float* __restrict__ out) {
  const int r = blockIdx.x * 64 + threadIdx.x;    // 256 x 64 = 16384 (z,row) pairs
  const int z = r >> 13, row = r & (N - 1);
  const float* __restrict__ base = part + (size_t)(z * NCHUNK) * N + row;
  float s0 = base[0];
  float s1 = base[(size_t)1 * N];
  float s2 = base[(size_t)2 * N];
  float s3 = base[(size_t)3 * N];
  const float s = (s0 + s1) + (s2 + s3);
  float val = z ? logf(s) : log1pf(s);
#pragma unroll
  for (int m = 1; m < 64; m <<= 1) val += __shfl_xor(val, m);
  if (threadIdx.x == 0) atomicAdd(out, val * (1.0f / (float)N));
}

extern "C" void kernel_launch(void* const* d_in, const int* in_sizes, int n_in,
                              void* d_out, int out_size, void* d_ws, size_t ws_size,
                              hipStream_t stream) {
  const float* e = (const float*)d_in[0];
  const float* p = (const float*)d_in[1];
  const float* n = (const float*)d_in[2];

  char* w = (char*)d_ws;
  uint8_t* eb = (uint8_t*)w;                                     // 2 MB
  uint8_t* pb = eb + (size_t)N * D;                              // 2 MB
  uint8_t* nb = pb + (size_t)N * D;                              // 2 MB
  float* cbuf = (float*)(nb + (size_t)N * D);                    // 32 KB
  float* part = cbuf + N;                                        // 256 KB

  normalize_kernel<<<N / 4, 256, 0, stream>>>(e, p, n, (uint32_t*)eb, (uint32_t*)pb,
                                              (uint32_t*)nb, cbuf, (float*)d_out);
  simexp_kernel<<<dim3(NCHUNK, N / BM, 2), 256, 0, stream>>>(eb, pb, nb, cbuf, part);
  finalize_kernel<<<256, 64, 0, stream>>>(part, (float*)d_out);
}

// Round 13
// 115.045 us; speedup vs baseline: 1.2411x; 1.0214x over previous
//
#include <hip/hip_runtime.h>
#include <stdint.h>

#define N 8192
#define D 256          // elements per row == bytes per fp8 row
#define INV_T 20.0f
#define LOG2E 1.44269504088896340736f
#define BM 128
#define BN 128
#define NCHUNK 4       // col-chunks (grid.x)
#define NT 16          // col-tiles per chunk; NCHUNK*NT*BN == N

typedef __attribute__((ext_vector_type(16))) float f32x16;
typedef __attribute__((ext_vector_type(4))) int i32x4;
typedef __attribute__((ext_vector_type(8))) int i32x8;

typedef __attribute__((address_space(3))) uint32_t lds_u32;
typedef __attribute__((address_space(1))) const uint32_t gbl_u32;

// Raw v_exp_f32 (2^x). Args bounded -> no OCML guard needed (verified r5).
static __device__ __forceinline__ float fast_exp2(float x) {
  float r;
  asm("v_exp_f32 %0, %1" : "=v"(r) : "v"(x));
  return r;
}

// Kernel 1: per-row fp32 normalize -> fp8 e4m3 copies (HW cvt, OCP on gfx950);
// c[i] = (e_i . p_i)/T exact fp32. Zeroes out (stream-ordered; replay-safe).
__global__ __launch_bounds__(256) void normalize_kernel(
    const float* __restrict__ e, const float* __restrict__ p, const float* __restrict__ n,
    uint32_t* __restrict__ eb, uint32_t* __restrict__ pb, uint32_t* __restrict__ nb,
    float* __restrict__ cbuf, float* __restrict__ out) {
  const int tid = threadIdx.x;
  const int wave = tid >> 6, lane = tid & 63;
  const int row = blockIdx.x * 4 + wave;          // one wave per row

  if (blockIdx.x == 0 && tid == 0) out[0] = 0.0f;

  const float4 ev = ((const float4*)(e + (size_t)row * D))[lane];
  const float4 pv = ((const float4*)(p + (size_t)row * D))[lane];
  const float4 nv = ((const float4*)(n + (size_t)row * D))[lane];

  float sse = ev.x*ev.x + ev.y*ev.y + ev.z*ev.z + ev.w*ev.w;
  float ssp = pv.x*pv.x + pv.y*pv.y + pv.z*pv.z + pv.w*pv.w;
  float ssn = nv.x*nv.x + nv.y*nv.y + nv.z*nv.z + nv.w*nv.w;
  float dep = ev.x*pv.x + ev.y*pv.y + ev.z*pv.z + ev.w*pv.w;
#pragma unroll
  for (int m = 1; m < 64; m <<= 1) {
    sse += __shfl_xor(sse, m);
    ssp += __shfl_xor(ssp, m);
    ssn += __shfl_xor(ssn, m);
    dep += __shfl_xor(dep, m);
  }
  const float se = 1.0f / fmaxf(sqrtf(sse), 1e-8f);
  const float sp = 1.0f / fmaxf(sqrtf(ssp), 1e-8f);
  const float sn = 1.0f / fmaxf(sqrtf(ssn), 1e-8f);

  int ue = __builtin_amdgcn_cvt_pk_fp8_f32(ev.x*se, ev.y*se, 0, false);
  ue     = __builtin_amdgcn_cvt_pk_fp8_f32(ev.z*se, ev.w*se, ue, true);
  int up = __builtin_amdgcn_cvt_pk_fp8_f32(pv.x*sp, pv.y*sp, 0, false);
  up     = __builtin_amdgcn_cvt_pk_fp8_f32(pv.z*sp, pv.w*sp, up, true);
  int un = __builtin_amdgcn_cvt_pk_fp8_f32(nv.x*sn, nv.y*sn, 0, false);
  un     = __builtin_amdgcn_cvt_pk_fp8_f32(nv.z*sn, nv.w*sn, un, true);
  eb[row * 64 + lane] = (uint32_t)ue;             // 64 uints = 256 fp8 bytes per row
  pb[row * 64 + lane] = (uint32_t)up;
  nb[row * 64 + lane] = (uint32_t)un;

  if (lane == 0) cbuf[row] = dep * se * sp * INV_T;
}

// Kernel 2: PERSISTENT col-walk fp8 GEMM (X @ Y^T) with fused exp row-sums.
// r12 pipeline (counted-vmcnt B double-buffer, 16-slot XOR layout = 0 bank
// conflicts, swapped MFMA = lane owns A-row, MX-scaled 32x32x64 = bit-exact
// 2x rate, raw v_exp_f32; 512 blocks = 2/CU, one dispatch batch) with 2x2
// WAVE TILING (r13): wave (wr,wc) owns a 64x64 sub-tile instead of 32x128.
// r12's waves each read the ENTIRE 128-col B tile (4x redundant; DS-read pipe
// = 20.5 us/CU was the largest demand). Now each wave reads only its 64 cols:
// 16 b128/tile (was 32) -> DS demand halves. A-frags grow to 64 VGPR (2 row
// groups); total ~150-165 VGPR, far from the 256 cap (r2/r7 spill territory
// starts ~220). Row-sums need a cross-wave combine: 1 KB LDS, once per block.
// Spill sentinels: VGPR <= ~190, WRITE_SIZE ~256 KB.
__global__ __launch_bounds__(256, 2) void simexp_kernel(
    const uint8_t* __restrict__ eb, const uint8_t* __restrict__ pb,
    const uint8_t* __restrict__ nb, const float* __restrict__ cbuf,
    float* __restrict__ part) {
  __shared__ uint8_t Bs[2][BN * D];   // 64 KB
  __shared__ float sm[2][BM];         // 1 KB: per-wc row partials

  const int z = blockIdx.z;
  const uint8_t* __restrict__ A = z ? pb : eb;
  const uint8_t* __restrict__ B = z ? eb : nb;

  const int tid = threadIdx.x;
  const int wave = tid >> 6, lane = tid & 63;
  const int lane31 = lane & 31, half = lane >> 5;
  const int wr = wave >> 1, wc = wave & 1;        // wave -> 64x64 sub-tile
  const int chunk = blockIdx.x;
  const int rowTile = blockIdx.y * BM;
  const int colblk0 = chunk * NT;

#define STAGEB(buf, cblk)                                                     \
  do {                                                                        \
    const uint8_t* __restrict__ Bsrc = B + (size_t)(cblk) * (BN * D);         \
    _Pragma("unroll") for (int i = 0; i < 8; ++i) {                           \
      const int c = i * 256 + tid, r = c >> 4, sl = c & 15;                   \
      const int gg = sl ^ (r & 15);                                           \
      __builtin_amdgcn_global_load_lds(                                       \
          (gbl_u32*)(Bsrc + (size_t)r * D + gg * 16),                         \
          (lds_u32*)&Bs[buf][c * 16], 16, 0, 0);                              \
    }                                                                         \
  } while (0)

  // ---- prologue: A-frags (2 row-groups) + cv FIRST (oldest in the vmem
  //      FIFO, drained by the first in-loop vmcnt), then B0, B1 ----
  i32x8 afr[2][4];
  float cv[2];
#pragma unroll
  for (int rg = 0; rg < 2; ++rg) {
    const int arow = rowTile + wr * 64 + rg * 32 + lane31;
    const uint8_t* __restrict__ Arow = A + (size_t)arow * D + half * 32;
#pragma unroll
    for (int s = 0; s < 4; ++s) {
      const i32x4 lo = *(const i32x4*)(Arow + s * 64);
      const i32x4 hi = *(const i32x4*)(Arow + s * 64 + 16);
      afr[rg][s] = (i32x8){lo[0], lo[1], lo[2], lo[3], hi[0], hi[1], hi[2], hi[3]};
    }
    cv[rg] = cbuf[arow] * LOG2E;
  }
  __builtin_amdgcn_sched_barrier(0);   // pin A/cv issue BEFORE the stages
  STAGEB(0, colblk0 + 0);
  STAGEB(1, colblk0 + 1);
  __builtin_amdgcn_sched_barrier(0);   // pin stages above the loop

  // per-cg XOR-folded B fragment base addresses (bit 15 = buffer parity, clear)
  int bbase[2];
#pragma unroll
  for (int cg = 0; cg < 2; ++cg) {
    const int cl = wc * 64 + cg * 32 + lane31;
    bbase[cg] = (cl << 8) ^ ((cl & 15) << 4) ^ (half << 5);
  }

  const float K2 = INV_T * LOG2E;
  float sacc[4];                       // [rg*2+cg], 4 independent chains
#pragma unroll
  for (int i = 0; i < 4; ++i) sacc[i] = 0.0f;

#pragma unroll 1
  for (int t = 0; t < NT; ++t) {
    // B_t landed when <=8 vmem outstanding (FIFO retire; A/cv are oldest).
    if (t < NT - 1) asm volatile("s_waitcnt vmcnt(8)" ::: "memory");
    else            asm volatile("s_waitcnt vmcnt(0)" ::: "memory");
    __builtin_amdgcn_s_barrier();
    __builtin_amdgcn_sched_barrier(0);

    const int bpar = (t & 1) << 15;
    f32x16 acc[2][2];
#pragma unroll
    for (int rg = 0; rg < 2; ++rg)
#pragma unroll
      for (int cg = 0; cg < 2; ++cg)
#pragma unroll
        for (int r = 0; r < 16; ++r) acc[rg][cg][r] = 0.0f;

#pragma unroll
    for (int s = 0; s < 4; ++s) {
      i32x8 b[2];
#pragma unroll
      for (int cg = 0; cg < 2; ++cg) {
        const int alo = (bbase[cg] ^ bpar) ^ (s << 6);
        const i32x4 blo = *(const i32x4*)&Bs[0][alo];
        const i32x4 bhi = *(const i32x4*)&Bs[0][alo ^ 16];
        b[cg] = (i32x8){blo[0], blo[1], blo[2], blo[3],
                        bhi[0], bhi[1], bhi[2], bhi[3]};
      }
#pragma unroll
      for (int rg = 0; rg < 2; ++rg)
#pragma unroll
        for (int cg = 0; cg < 2; ++cg)
          acc[rg][cg] = __builtin_amdgcn_mfma_scale_f32_32x32x64_f8f6f4(
              b[cg], afr[rg][s], acc[rg][cg],   // SWAPPED: lane -> A-row
              0 /*fmt fp8*/, 0 /*fmt fp8*/,
              0, 0x7F7F7F7F /*scale=1*/, 0, 0x7F7F7F7F /*scale=1*/);
    }

    __builtin_amdgcn_sched_barrier(0);
    __builtin_amdgcn_s_barrier();   // all waves done reading buf (t&1)
    __builtin_amdgcn_sched_barrier(0);

    if (t + 2 < NT) STAGEB(t & 1, colblk0 + t + 2);  // refill vacated buffer

    // exp-accumulate (VALU) overlaps the staging just issued.
#pragma unroll
    for (int reg = 0; reg < 16; ++reg) {
      sacc[0] += fast_exp2(acc[0][0][reg] * K2 - cv[0]);
      sacc[1] += fast_exp2(acc[0][1][reg] * K2 - cv[0]);
      sacc[2] += fast_exp2(acc[1][0][reg] * K2 - cv[1]);
      sacc[3] += fast_exp2(acc[1][1][reg] * K2 - cv[1]);
    }
  }
#undef STAGEB

  // ---- once per block: combine halves in-lane, then cross-wave via LDS ----
  float v0 = sacc[0] + sacc[1];        // rg=0 rows, this wave's 64 cols (half set)
  float v1 = sacc[2] + sacc[3];        // rg=1 rows
  v0 += __shfl_xor(v0, 32);            // + complementary col subset (other half)
  v1 += __shfl_xor(v1, 32);
  if (lane < 32) {
    sm[wc][wr * 64 + lane] = v0;       // row = wr*64 + 0*32 + lane
    sm[wc][wr * 64 + 32 + lane] = v1;  // row = wr*64 + 1*32 + lane
  }
  __syncthreads();
  if (tid < BM)
    part[((size_t)(z * NCHUNK + chunk)) * N + rowTile + tid] =
        sm[0][tid] + sm[1][tid];
}

// Kernel 3 (finalize): per-row sum of 4 partials -> log/log1p -> wave reduce
// -> one atomicAdd per 64-thread block (256 atomics to out). No fences needed:
// part is written with plain stores; the launch boundary orders visibility.
__global__ __launch_bounds__(64) void finalize_kernel(const float* __restrict__ part,
                                                      float* __restrict__ out) {
  const int r = blockIdx.x * 64 + threadIdx.x;    // 256 x 64 = 16384 (z,row) pairs
  const int z = r >> 13, row = r & (N - 1);
  const float* __restrict__ base = part + (size_t)(z * NCHUNK) * N + row;
  float s0 = base[0];
  float s1 = base[(size_t)1 * N];
  float s2 = base[(size_t)2 * N];
  float s3 = base[(size_t)3 * N];
  const float s = (s0 + s1) + (s2 + s3);
  float val = z ? logf(s) : log1pf(s);
#pragma unroll
  for (int m = 1; m < 64; m <<= 1) val += __shfl_xor(val, m);
  if (threadIdx.x == 0) atomicAdd(out, val * (1.0f / (float)N));
}

extern "C" void kernel_launch(void* const* d_in, const int* in_sizes, int n_in,
                              void* d_out, int out_size, void* d_ws, size_t ws_size,
                              hipStream_t stream) {
  const float* e = (const float*)d_in[0];
  const float* p = (const float*)d_in[1];
  const float* n = (const float*)d_in[2];

  char* w = (char*)d_ws;
  uint8_t* eb = (uint8_t*)w;                                     // 2 MB
  uint8_t* pb = eb + (size_t)N * D;                              // 2 MB
  uint8_t* nb = pb + (size_t)N * D;                              // 2 MB
  float* cbuf = (float*)(nb + (size_t)N * D);                    // 32 KB
  float* part = cbuf + N;                                        // 256 KB

  normalize_kernel<<<N / 4, 256, 0, stream>>>(e, p, n, (uint32_t*)eb, (uint32_t*)pb,
                                              (uint32_t*)nb, cbuf, (float*)d_out);
  simexp_kernel<<<dim3(NCHUNK, N / BM, 2), 256, 0, stream>>>(eb, pb, nb, cbuf, part);
  finalize_kernel<<<256, 64, 0, stream>>>(part, (float*)d_out);
}